// Round 5
// baseline (288.313 us; speedup 1.0000x reference)
//
#include <hip/hip_runtime.h>

// VQ-VAE codebook: z [32,64,32,32] f32 NCHW, embedding [1024,64] f32.
// Outputs (concat, f32): z_q NCHW (2097152) | indices as float (32768) | loss (1).
// N = 32768 rows (n = b*1024 + hw), D = 64, K = 1024.
// argmin_k ||z_n - e_k||^2 == argmin_k ( ||e_k||^2 - 2 z_n.e_k ).
//
// R5 design: R1-R4 were K$-latency-bound: the wave-uniform e-row address got
// scalarized to s_load (SGPR=112) and the scalar cache can't stream 256 KB.
// Fix: force e-rows onto VMEM (opaque VGPR zero in the address), double-buffer
// rows in VGPRs, 1-wave blocks, u64-packed atomicMin argmin merge.

#define DD 64
#define KK 1024
#define NROWS 32768
#define IDX_OFF 2097152
#define LOSS_OFF 2129920
#define BIGF 512.0f

__device__ float g_enormBig[KK];              // ||e_k||^2 + 512
__device__ unsigned long long g_keys[NROWS];  // (f32 key << 32) | k
__device__ float g_loss;

// ---------------- kernel 1: enorm + init keys/loss -------------------------
__global__ __launch_bounds__(256) void vq_prep(const float* __restrict__ e) {
    int tid = blockIdx.x * 256 + threadIdx.x;   // grid 128 -> 32768 threads
    if (tid < KK) {
        const float4* ek = (const float4*)(e + tid * DD);
        float s = 0.f;
#pragma unroll
        for (int j = 0; j < 16; ++j) {
            float4 v = ek[j];
            s += v.x * v.x + v.y * v.y + v.z * v.z + v.w * v.w;
        }
        g_enormBig[tid] = s + BIGF;
    }
    g_keys[tid] = 0xFFFFFFFFFFFFFFFFull;
    if (tid == 0) g_loss = 0.f;
}

// ---------------- kernel 2: main — distances + packed argmin ---------------
// 1-wave blocks: bid = rowgroup*8 + slice. Wave handles 64 rows (lane=row),
// scans k in [slice*128, slice*128+128). e-rows double-buffered in VGPRs via
// VMEM broadcast loads (opaque zero defeats uniform->s_load scalarization).
__global__ __launch_bounds__(64, 2) void vq_main(const float* __restrict__ z,
                                                 const float* __restrict__ e) {
    int lane = threadIdx.x;
    int bid  = blockIdx.x;          // 0..4095
    int s    = bid & 7;             // k-slice (also the XCD -> L2-local e slice)
    int rg   = bid >> 3;            // rowgroup 0..511
    int b    = rg >> 4;
    int hw0  = (rg & 15) << 6;
    int k0   = s << 7;

    // opaque zero in a VGPR: compiler cannot prove e addresses uniform -> VMEM
    int vzero;
    asm("v_mov_b32 %0, 0" : "=v"(vzero));

    const float* zbase = z + (size_t)b * 65536 + hw0 + lane;

    float4 zr[16];
#pragma unroll
    for (int j = 0; j < 16; ++j) {
        float4 t;
        t.x = zbase[(j * 4 + 0) * 1024];
        t.y = zbase[(j * 4 + 1) * 1024];
        t.z = zbase[(j * 4 + 2) * 1024];
        t.w = zbase[(j * 4 + 3) * 1024];
        zr[j] = t;
    }

    const float4* e4 = (const float4*)e + vzero;   // divergent-typed base
    const float*  en = g_enormBig + vzero;

    float4 eA[16], eB[16];
    float  enA, enB;
#pragma unroll
    for (int j = 0; j < 16; ++j) eA[j] = e4[k0 * 16 + j];
    enA = en[k0];

    float bestv = 3.4e38f;
    int   besti = k0;

    for (int kk = 0; kk < 64; ++kk) {
        int k   = k0 + kk * 2;
        int kn1 = k + 1;
#pragma unroll
        for (int j = 0; j < 16; ++j) eB[j] = e4[kn1 * 16 + j];
        enB = en[kn1];

        {   // row k from eA
            float d0 = 0.f, d1 = 0.f, d2 = 0.f, d3 = 0.f;
#pragma unroll
            for (int j = 0; j < 16; ++j) {
                d0 = fmaf(zr[j].x, eA[j].x, d0);
                d1 = fmaf(zr[j].y, eA[j].y, d1);
                d2 = fmaf(zr[j].z, eA[j].z, d2);
                d3 = fmaf(zr[j].w, eA[j].w, d3);
            }
            float cand = fmaf(-2.f, (d0 + d1) + (d2 + d3), enA);
            if (cand < bestv) { bestv = cand; besti = k; }   // strict <: first-min
        }

        int kn2 = k + 2;                       // prefetch overrun on last iter:
        kn2 = kn2 > (KK - 1) ? (KK - 1) : kn2; // clamp (slice 7 only)
#pragma unroll
        for (int j = 0; j < 16; ++j) eA[j] = e4[kn2 * 16 + j];
        enA = en[kn2];

        {   // row k+1 from eB
            float d0 = 0.f, d1 = 0.f, d2 = 0.f, d3 = 0.f;
#pragma unroll
            for (int j = 0; j < 16; ++j) {
                d0 = fmaf(zr[j].x, eB[j].x, d0);
                d1 = fmaf(zr[j].y, eB[j].y, d1);
                d2 = fmaf(zr[j].z, eB[j].z, d2);
                d3 = fmaf(zr[j].w, eB[j].w, d3);
            }
            float cand = fmaf(-2.f, (d0 + d1) + (d2 + d3), enB);
            if (cand < bestv) { bestv = cand; besti = kn1; }
        }
    }

    // bestv = 512 + ||e||^2 - 2 z.e > 0 always (||z||^2 << 512) -> uint order
    // equals float order; low bits carry k so min => smallest k on ties.
    unsigned long long key =
        ((unsigned long long)__float_as_uint(bestv) << 32) | (unsigned)besti;
    atomicMin(&g_keys[rg * 64 + lane], key);
}

// ---------------- kernel 3: finalize — z_q, indices, loss ------------------
// block = 256 thr (4 waves) per rowgroup of 64 rows; wave w covers d=16w..16w+15.
__global__ __launch_bounds__(256) void vq_fin(const float* __restrict__ z,
                                              const float* __restrict__ e,
                                              float* __restrict__ out) {
    int lane = threadIdx.x & 63;
    int w    = threadIdx.x >> 6;
    int rg   = blockIdx.x;          // 0..511
    int n    = rg * 64 + lane;
    int b    = rg >> 4;
    int hw0  = (rg & 15) << 6;

    unsigned long long key = g_keys[n];
    int idx = (int)(key & 0xFFFFFFFFull);
    if (w == 0) out[IDX_OFF + n] = (float)idx;

    const float* zbase = z + (size_t)b * 65536 + hw0 + lane;
    float*       qbase = out + (size_t)b * 65536 + hw0 + lane;
    const float* er    = e + (size_t)idx * DD;

    float lsum = 0.f;
#pragma unroll
    for (int j = 0; j < 16; ++j) {
        int d = w * 16 + j;
        float ev = er[d];                     // gather, L2-resident
        float zv = zbase[(size_t)d * 1024];
        float df = ev - zv;
        lsum = fmaf(df, df, lsum);
        qbase[(size_t)d * 1024] = ev;         // coalesced along hw
    }
#pragma unroll
    for (int o = 32; o; o >>= 1) lsum += __shfl_xor(lsum, o, 64);
    if (lane == 0) atomicAdd(&g_loss, lsum);
}

// ---------------- kernel 4: loss scalar ------------------------------------
__global__ void vq_finish(float* __restrict__ out) {
    // loss = q_latent + 0.25*e_latent = 1.25 * mean((z_q - z)^2)
    out[LOSS_OFF] = g_loss * (1.25f / 2097152.0f);
}

extern "C" void kernel_launch(void* const* d_in, const int* in_sizes, int n_in,
                              void* d_out, int out_size, void* d_ws, size_t ws_size,
                              hipStream_t stream) {
    const float* z = (const float*)d_in[0];
    const float* e = (const float*)d_in[1];
    float* out = (float*)d_out;

    vq_prep<<<128, 256, 0, stream>>>(e);
    vq_main<<<4096, 64, 0, stream>>>(z, e);
    vq_fin<<<512, 256, 0, stream>>>(z, e, out);
    vq_finish<<<1, 1, 0, stream>>>(out);
}

// Round 6
// 137.662 us; speedup vs baseline: 2.0944x; 2.0944x over previous
//
#include <hip/hip_runtime.h>

// VQ-VAE codebook: z [32,64,32,32] f32 NCHW, embedding [1024,64] f32.
// Outputs (concat, f32): z_q NCHW (2097152) | indices as float (32768) | loss (1).
// N = 32768 rows (n = b*1024 + hw), D = 64, K = 1024.
// argmin_k ||z_n - e_k||^2 == argmin_k ( (||e_k||^2+512) - 2 z_n.e_k )  per row.
//
// R6 design: R1-R5 showed (a) SMEM can't stream e, (b) per-lane VMEM broadcast
// can't either, (c) loaded-value register arrays get demoted by the backend.
// => LDS-staged GEMM with ACCUMULATOR-only register pressure: acc[8][8]/lane,
// z in LDS [d][row], e-tiles in LDS [d][k] (pad 68), 4x ds_read_b128 per
// 64 v_fma (1 B/FMA). Argmin fused: per-lane best across tiles, final u64
// shfl-reduce + atomicMin (bias +512 keeps keys positive; low bits = k so
// ties -> smallest k = np.argmin first-min semantics).

#define DD 64
#define KK 1024
#define NROWS 32768
#define IDX_OFF 2097152
#define LOSS_OFF 2129920
#define BIGF 512.0f

__device__ float g_enormBig[KK];              // ||e_k||^2 + 512
__device__ unsigned long long g_keys[NROWS];  // (f32 key << 32) | k
__device__ float g_loss;

// ---------------- kernel 1: enorm + init keys/loss -------------------------
__global__ __launch_bounds__(256) void vq_prep(const float* __restrict__ e) {
    int tid = blockIdx.x * 256 + threadIdx.x;   // grid 128 -> 32768 threads
    if (tid < KK) {
        const float4* ek = (const float4*)(e + tid * DD);
        float s = 0.f;
#pragma unroll
        for (int j = 0; j < 16; ++j) {
            float4 v = ek[j];
            s += v.x * v.x + v.y * v.y + v.z * v.z + v.w * v.w;
        }
        g_enormBig[tid] = s + BIGF;
    }
    g_keys[tid] = 0xFFFFFFFFFFFFFFFFull;
    if (tid == 0) g_loss = 0.f;
}

// ---------------- kernel 2: main — LDS GEMM + fused argmin -----------------
// grid 512: bid = rg*2 + h. Block: 128 thr (2 waves), 128 rows, k in
// [h*512, h*512+512) as 8 tiles of 64. Lane (lr=lane>>3, lc=lane&7) owns
// rows wo+lr*8+j (j<8) x ks lc*8+m (m<8).
__global__ __launch_bounds__(128, 2) void vq_main(const float* __restrict__ z,
                                                  const float* __restrict__ e) {
    __shared__ float zt[64][128];   // [d][row]  32 KB
    __shared__ float et[64][68];    // [d][k] pad->68 (16B-aligned rows) 17 KB
    __shared__ float enb[512];      // biased enorm for this k-half  2 KB

    int t    = threadIdx.x;         // 0..127
    int lane = t & 63;
    int wo   = (t >> 6) * 64;       // wave row offset: 0 or 64
    int lr   = lane >> 3;           // 0..7
    int lc   = lane & 7;            // 0..7
    int bid  = blockIdx.x;          // 0..511
    int h    = bid & 1;             // k-half
    int rg   = bid >> 1;            // 0..255
    int b    = rg >> 3;
    int hw0  = (rg & 7) << 7;       // *128
    int kb0  = h << 9;              // h*512

    // ---- stage z [d][row] (flat coalesced copy: global layout matches) ----
    {
        const float* zg = z + (size_t)b * 65536 + hw0;
#pragma unroll
        for (int p = 0; p < 16; ++p) {
            int d = 4 * p + (t >> 5);
            int i = (t & 31) * 4;
            *(float4*)&zt[d][i] = *(const float4*)&zg[d * 1024 + i];
        }
        *(float4*)&enb[t * 4] = *(const float4*)&g_enormBig[kb0 + t * 4];
    }

    float best[8];
    int   bi[8];
#pragma unroll
    for (int j = 0; j < 8; ++j) { best[j] = 3.4e38f; bi[j] = 0; }

    __syncthreads();

    for (int tt = 0; tt < 8; ++tt) {
        int kb = kb0 + tt * 64;
        // ---- stage e-tile transposed: et[d][kk] ----
        {
            const float* eg = e + (size_t)kb * DD;
#pragma unroll
            for (int p = 0; p < 8; ++p) {
                int kk = p * 8 + (t >> 4);       // 0..63
                int d0 = (t & 15) * 4;
                float4 v = *(const float4*)&eg[kk * DD + d0];
                et[d0 + 0][kk] = v.x;
                et[d0 + 1][kk] = v.y;
                et[d0 + 2][kk] = v.z;
                et[d0 + 3][kk] = v.w;
            }
        }
        __syncthreads();

        float acc[8][8];
#pragma unroll
        for (int j = 0; j < 8; ++j)
#pragma unroll
            for (int m = 0; m < 8; ++m) acc[j][m] = 0.f;

#pragma unroll 4
        for (int d = 0; d < 64; ++d) {
            float4 za0 = *(float4*)&zt[d][wo + lr * 8];
            float4 za1 = *(float4*)&zt[d][wo + lr * 8 + 4];
            float4 eb0 = *(float4*)&et[d][lc * 8];
            float4 eb1 = *(float4*)&et[d][lc * 8 + 4];
            float za[8] = {za0.x, za0.y, za0.z, za0.w, za1.x, za1.y, za1.z, za1.w};
            float eb[8] = {eb0.x, eb0.y, eb0.z, eb0.w, eb1.x, eb1.y, eb1.z, eb1.w};
#pragma unroll
            for (int j = 0; j < 8; ++j)
#pragma unroll
                for (int m = 0; m < 8; ++m)
                    acc[j][m] = fmaf(za[j], eb[m], acc[j][m]);
        }

        // ---- merge tile into per-lane running best (k ascending: tt, m) ----
        float4 en0 = *(float4*)&enb[tt * 64 + lc * 8];
        float4 en1 = *(float4*)&enb[tt * 64 + lc * 8 + 4];
        float en[8] = {en0.x, en0.y, en0.z, en0.w, en1.x, en1.y, en1.z, en1.w};
#pragma unroll
        for (int j = 0; j < 8; ++j)
#pragma unroll
            for (int m = 0; m < 8; ++m) {
                float cand = fmaf(-2.f, acc[j][m], en[m]);
                if (cand < best[j]) { best[j] = cand; bi[j] = kb + lc * 8 + m; }
            }
        __syncthreads();   // all waves done reading et before next stage
    }

    // ---- cross-lane argmin over lc (lane bits 0..2), then global merge ----
#pragma unroll
    for (int j = 0; j < 8; ++j) {
        unsigned long long key =
            ((unsigned long long)__float_as_uint(best[j]) << 32) | (unsigned)bi[j];
#pragma unroll
        for (int o = 1; o < 8; o <<= 1) {
            unsigned long long other = __shfl_xor(key, o, 64);
            key = other < key ? other : key;
        }
        if (lc == 0)
            atomicMin(&g_keys[rg * 128 + wo + lr * 8 + j], key);
    }
}

// ---------------- kernel 3: finalize — z_q, indices, loss ------------------
// block = 256 thr (4 waves) per rowgroup of 64 rows; wave w covers d=16w..16w+15.
__global__ __launch_bounds__(256) void vq_fin(const float* __restrict__ z,
                                              const float* __restrict__ e,
                                              float* __restrict__ out) {
    int lane = threadIdx.x & 63;
    int w    = threadIdx.x >> 6;
    int rg   = blockIdx.x;          // 0..511
    int n    = rg * 64 + lane;
    int b    = rg >> 4;
    int hw0  = (rg & 15) << 6;

    unsigned long long key = g_keys[n];
    int idx = (int)(key & 0xFFFFFFFFull);
    if (w == 0) out[IDX_OFF + n] = (float)idx;

    const float* zbase = z + (size_t)b * 65536 + hw0 + lane;
    float*       qbase = out + (size_t)b * 65536 + hw0 + lane;
    const float* er    = e + (size_t)idx * DD;

    float lsum = 0.f;
#pragma unroll
    for (int j = 0; j < 16; ++j) {
        int d = w * 16 + j;
        float ev = er[d];                     // gather, L2-resident
        float zv = zbase[(size_t)d * 1024];
        float df = ev - zv;
        lsum = fmaf(df, df, lsum);
        qbase[(size_t)d * 1024] = ev;         // coalesced along hw
    }
#pragma unroll
    for (int o = 32; o; o >>= 1) lsum += __shfl_xor(lsum, o, 64);
    if (lane == 0) atomicAdd(&g_loss, lsum);
}

// ---------------- kernel 4: loss scalar ------------------------------------
__global__ void vq_finish(float* __restrict__ out) {
    // loss = q_latent + 0.25*e_latent = 1.25 * mean((z_q - z)^2)
    out[LOSS_OFF] = g_loss * (1.25f / 2097152.0f);
}

extern "C" void kernel_launch(void* const* d_in, const int* in_sizes, int n_in,
                              void* d_out, int out_size, void* d_ws, size_t ws_size,
                              hipStream_t stream) {
    const float* z = (const float*)d_in[0];
    const float* e = (const float*)d_in[1];
    float* out = (float*)d_out;

    vq_prep<<<128, 256, 0, stream>>>(e);
    vq_main<<<512, 128, 0, stream>>>(z, e);
    vq_fin<<<512, 256, 0, stream>>>(z, e, out);
    vq_finish<<<1, 1, 0, stream>>>(out);
}

// Round 8
// 85.430 us; speedup vs baseline: 3.3748x; 1.6114x over previous
//
#include <hip/hip_runtime.h>

// VQ-VAE codebook: z [32,64,32,32] f32 NCHW, embedding [1024,64] f32.
// Outputs (concat, f32): z_q NCHW (2097152) | indices as float (32768) | loss (1).
// N = 32768 rows (n = b*1024 + hw), D = 64, K = 1024.
// argmin_k ||z_n - e_k||^2 == argmin_k ( (||e_k||^2+512) - 2 z_n.e_k ) per row.
//
// R8: R7 had a wave race — waves sharing rows but covering different
// k-quarters stored to the same g_half slot (last-writer-wins -> wrong argmin).
// Fix: one partial slot per (k-half h, k-quarter q) domain: g_part[h][q][n],
// each written by exactly one wave; vq_fin merges 4 keys by u64-min
// (positive-biased dist in high bits, k in low bits -> ties pick smallest k,
// matching np.argmin first-min semantics).

#define DD 64
#define KK 1024
#define NROWS 32768
#define IDX_OFF 2097152
#define LOSS_OFF 2129920
#define BIGF 512.0f

__device__ unsigned long long g_part[2][2][NROWS]; // [k-half][k-quarter][row]
__device__ float g_partial[512];                   // per-rowgroup loss partials

typedef const __attribute__((address_space(1))) void* gvp;
typedef __attribute__((address_space(3))) void* lvp;

__device__ __forceinline__ void gll4(const float* g, float* l) {
    __builtin_amdgcn_global_load_lds((gvp)(const void*)g, (lvp)(void*)l, 4, 0, 0);
}
__device__ __forceinline__ void gll16(const float* g, float* l) {
    __builtin_amdgcn_global_load_lds((gvp)(const void*)g, (lvp)(void*)l, 16, 0, 0);
}

// ---------------- kernel 1: main — LDS GEMM + fused argmin -----------------
// grid 512: bid = h*256 + rg. Block: 256 thr (4 waves), 128 rows, k-half 512
// as 8 tiles of 64 ks (double-buffered). Wave w: row-half w&1, k-quarter w>>1.
// Lane: lr=lane>>3 -> 8 rows, lc=lane&7 -> 4 ks. acc[8][4] per lane.
__global__ __launch_bounds__(256, 2) void vq_main(const float* __restrict__ z,
                                                  const float* __restrict__ e) {
    __shared__ float zt[64][128];     // [d][row]        32 KB
    __shared__ float et[2][64][68];   // [buf][d][kk]    34.8 KB (pad 68)
    __shared__ float enb[512];        // ||e||^2 + 512    2 KB

    const int t    = threadIdx.x;
    const int lane = t & 63;
    const int w    = __builtin_amdgcn_readfirstlane(t >> 6);  // 0..3
    const int lr   = lane >> 3;       // 0..7
    const int lc   = lane & 7;        // 0..7
    const int bid  = blockIdx.x;
    const int rg   = bid & 255;       // rowgroup (128 rows)
    const int h    = bid >> 8;        // k-half
    const int q    = w >> 1;          // k-quarter owner (0/1)
    const int b    = rg >> 3;
    const int hw0  = (rg & 7) << 7;
    const int kb0  = h << 9;
    const int h64  = (w & 1) << 6;    // wave's row-half offset
    const int q32  = q << 5;          // wave's k-quarter offset within tile

    const float* zg = z + (size_t)b * 65536 + hw0;

    // ---- stage zt via DMA (wave w: d-pairs; 1024B linear per issue) ----
#pragma unroll
    for (int j = 0; j < 8; ++j) {
        int d0 = (((w << 3) + j) << 1);
        gll16(zg + (size_t)(d0 + (lane >> 5)) * 1024 + ((lane & 31) << 2), &zt[d0][0]);
    }
    // ---- stage et buf0 tile0 via DMA (wave w: d = 16w..16w+15) ----
#pragma unroll
    for (int i = 0; i < 16; ++i) {
        int d = (w << 4) + i;
        gll4(e + (size_t)(kb0 + lane) * 64 + d, &et[0][d][0]);
    }
    // ---- enb: thread t computes kk = t and t+256 (L2-resident reads) ----
#pragma unroll
    for (int r = 0; r < 2; ++r) {
        int kk = t + (r << 8);
        const float4* ep = (const float4*)(e + (size_t)(kb0 + kk) * 64);
        float s0 = 0.f, s1 = 0.f, s2 = 0.f, s3 = 0.f;
#pragma unroll
        for (int j = 0; j < 16; ++j) {
            float4 v = ep[j];
            s0 = fmaf(v.x, v.x, s0); s1 = fmaf(v.y, v.y, s1);
            s2 = fmaf(v.z, v.z, s2); s3 = fmaf(v.w, v.w, s3);
        }
        enb[kk] = (s0 + s1) + (s2 + s3) + BIGF;
    }

    float best[8];
    int   bi[8];
#pragma unroll
    for (int j = 0; j < 8; ++j) { best[j] = 3.4e38f; bi[j] = 0; }

    __syncthreads();   // drains DMA (vmcnt) + enb writes

    for (int tt = 0; tt < 8; ++tt) {
        const int cur = tt & 1;
        // prefetch next tile into the other buffer (issued before compute;
        // L2 latency hides under ~8k cycles of FMA -> barrier drain is cheap)
        if (tt < 7) {
            int kb = kb0 + ((tt + 1) << 6);
#pragma unroll
            for (int i = 0; i < 16; ++i) {
                int d = (w << 4) + i;
                gll4(e + (size_t)(kb + lane) * 64 + d, &et[cur ^ 1][d][0]);
            }
        }

        const float (*etc)[68] = et[cur];
        float acc[8][4];
#pragma unroll
        for (int j = 0; j < 8; ++j) { acc[j][0] = 0.f; acc[j][1] = 0.f; acc[j][2] = 0.f; acc[j][3] = 0.f; }

#pragma unroll 8
        for (int d = 0; d < 64; ++d) {
            float4 a0 = *(const float4*)&zt[d][h64 + lr * 8];
            float4 a1 = *(const float4*)&zt[d][h64 + lr * 8 + 4];
            float4 b0 = *(const float4*)&etc[d][q32 + lc * 4];
            float za[8] = {a0.x, a0.y, a0.z, a0.w, a1.x, a1.y, a1.z, a1.w};
#pragma unroll
            for (int j = 0; j < 8; ++j) {
                acc[j][0] = fmaf(za[j], b0.x, acc[j][0]);
                acc[j][1] = fmaf(za[j], b0.y, acc[j][1]);
                acc[j][2] = fmaf(za[j], b0.z, acc[j][2]);
                acc[j][3] = fmaf(za[j], b0.w, acc[j][3]);
            }
        }

        // merge tile into running best (u64 tie-break handles ordering)
        const int kk0 = (tt << 6) + q32 + lc * 4;    // local k in [0,512)
#pragma unroll
        for (int j = 0; j < 8; ++j)
#pragma unroll
            for (int m = 0; m < 4; ++m) {
                float cand = fmaf(-2.f, acc[j][m], enb[kk0 + m]);
                if (cand < best[j]) { best[j] = cand; bi[j] = kb0 + kk0 + m; }
            }
        __syncthreads();
    }

    // cross-lane argmin over lc (partners share lr); u64 min => smaller k on tie
#pragma unroll
    for (int j = 0; j < 8; ++j) {
        unsigned long long key =
            ((unsigned long long)__float_as_uint(best[j]) << 32) | (unsigned)bi[j];
#pragma unroll
        for (int o = 1; o < 8; o <<= 1) {
            unsigned long long other = __shfl_xor(key, o, 64);
            key = other < key ? other : key;
        }
        if (lc == 0)   // one writer per (h, q, row): no race
            g_part[h][q][(size_t)rg * 128 + h64 + lr * 8 + j] = key;
    }
}

// ---------------- kernel 2: finalize — merge 4 partials, z_q, idx, loss ----
__global__ __launch_bounds__(256) void vq_fin(const float* __restrict__ z,
                                              const float* __restrict__ e,
                                              float* __restrict__ out) {
    __shared__ float lred[4];
    int lane = threadIdx.x & 63;
    int w    = threadIdx.x >> 6;
    int rg   = blockIdx.x;          // 0..511 rowgroups of 64
    int n    = rg * 64 + lane;
    int b    = rg >> 4;
    int hw0  = (rg & 15) << 6;

    unsigned long long k00 = g_part[0][0][n];
    unsigned long long k01 = g_part[0][1][n];
    unsigned long long k10 = g_part[1][0][n];
    unsigned long long k11 = g_part[1][1][n];
    unsigned long long key = k00;
    key = k01 < key ? k01 : key;
    key = k10 < key ? k10 : key;
    key = k11 < key ? k11 : key;    // u64 min: ties -> smallest k
    int idx = (int)(key & 0xFFFFFFFFull);
    if (w == 0) out[IDX_OFF + n] = (float)idx;

    const float*  zbase = z + (size_t)b * 65536 + hw0 + lane;
    float*        qbase = out + (size_t)b * 65536 + hw0 + lane;
    const float4* er4   = (const float4*)(e + (size_t)idx * 64) + (w << 2);

    float lsum = 0.f;
#pragma unroll
    for (int p = 0; p < 4; ++p) {
        float4 ev = er4[p];                        // gather, L2-resident
        int d = (w << 4) + (p << 2);
        float ezw[4] = {ev.x, ev.y, ev.z, ev.w};
#pragma unroll
        for (int qq = 0; qq < 4; ++qq) {
            float zv = zbase[(size_t)(d + qq) * 1024];
            float df = ezw[qq] - zv;
            lsum = fmaf(df, df, lsum);
            qbase[(size_t)(d + qq) * 1024] = ezw[qq]; // coalesced along hw
        }
    }
#pragma unroll
    for (int o = 32; o; o >>= 1) lsum += __shfl_xor(lsum, o, 64);
    if (lane == 0) lred[w] = lsum;
    __syncthreads();
    if (threadIdx.x == 0)
        g_partial[rg] = (lred[0] + lred[1]) + (lred[2] + lred[3]);
}

// ---------------- kernel 3: loss scalar ------------------------------------
__global__ __launch_bounds__(64) void vq_finish(float* __restrict__ out) {
    int lane = threadIdx.x;
    float s = 0.f;
#pragma unroll
    for (int i = 0; i < 8; ++i) s += g_partial[lane * 8 + i];
#pragma unroll
    for (int o = 32; o; o >>= 1) s += __shfl_xor(s, o, 64);
    // loss = q_latent + 0.25*e_latent = 1.25 * mean((z_q - z)^2)
    if (lane == 0) out[LOSS_OFF] = s * (1.25f / 2097152.0f);
}

extern "C" void kernel_launch(void* const* d_in, const int* in_sizes, int n_in,
                              void* d_out, int out_size, void* d_ws, size_t ws_size,
                              hipStream_t stream) {
    const float* z = (const float*)d_in[0];
    const float* e = (const float*)d_in[1];
    float* out = (float*)d_out;

    vq_main<<<512, 256, 0, stream>>>(z, e);
    vq_fin<<<512, 256, 0, stream>>>(z, e, out);
    vq_finish<<<1, 64, 0, stream>>>(out);
}

// Round 9
// 68.886 us; speedup vs baseline: 4.1853x; 1.2402x over previous
//
#include <hip/hip_runtime.h>

// VQ-VAE codebook: z [32,64,32,32] f32 NCHW, embedding [1024,64] f32.
// Outputs (concat, f32): z_q NCHW (2097152) | indices as float (32768) | loss (1).
// N = 32768 rows (n = b*1024 + hw), D = 64, K = 1024.
// dist(n,k) = ||e_k||^2 - 2 z_n.e_k (+512 bias)  = sum_d z_d*(-2 e_kd) + norm_k.
//
// R9: R8's cost was delivery, not FMA: transpose-staging scatter (gll4 x64
// lanes x64 lines), enb gather, and 3 b128 per 32 FMA. Fix: augmented e'
// rows [-2e | ||e||^2+512 | pad] staged as FLAT coalesced gll16 (no
// transpose, no enb), and 8x8 per-lane fragments (8+8 b128 per 256 FMA).
// 128row x 128k tiles, single-buffered; 2 blocks/CU interleave covers drain.

#define DD 64
#define KK 1024
#define NROWS 32768
#define IDX_OFF 2097152
#define LOSS_OFF 2129920
#define BIGF 512.0f
#define RL 72                       // e' row length in floats (288 B)

__device__ __align__(16) float g_ep[KK * RL];      // augmented codebook
__device__ unsigned long long g_part[2][2][NROWS]; // [k-half][k-quarter][row]
__device__ float g_partial[512];                   // per-rowgroup loss partials

typedef const __attribute__((address_space(1))) void* gvp;
typedef __attribute__((address_space(3))) void* lvp;

__device__ __forceinline__ void gll16(const float* g, float* l) {
    __builtin_amdgcn_global_load_lds((gvp)(const void*)g, (lvp)(void*)l, 16, 0, 0);
}

// ---------------- kernel 0: build e' ---------------------------------------
// 256 blocks x 256 thr: wave per row (4 rows/block).
__global__ __launch_bounds__(256) void vq_prep(const float* __restrict__ e) {
    int lane = threadIdx.x & 63;
    int k    = blockIdx.x * 4 + (threadIdx.x >> 6);
    float v  = e[k * DD + lane];
    float s  = v * v;
#pragma unroll
    for (int o = 32; o; o >>= 1) s += __shfl_xor(s, o, 64);
    float* row = g_ep + (size_t)k * RL;
    row[lane] = -2.0f * v;
    if (lane == 0)  row[64] = s + BIGF;
    if (lane >= 57) row[lane + 8] = 0.0f;   // cols 65..71
}

// ---------------- kernel 1: main — LDS GEMM + fused argmin -----------------
// grid 512: bid = h*256 + rg. Block: 256 thr (4 waves), 128 rows, k-half 512
// as 4 tiles of 128 ks (single-buffered e'). Wave w: row-half w&1 (h64),
// k-half-of-tile w>>1 (q64). Lane: lr=lane>>3 -> 8 rows, lc=lane&7; per-lane
// fragment acc[8][8]: rows h64+lr*8+j, ks q64 + m*8 + lc (m-major: lc-adjacent
// rows -> 2-way banks, free).
__global__ __launch_bounds__(256, 2) void vq_main(const float* __restrict__ z) {
    __shared__ float zt[64][128];      // [d][row]  32 KB
    __shared__ float et[128 * RL];     // e' tile, row-major flat  36.9 KB

    const int t    = threadIdx.x;
    const int lane = t & 63;
    const int w    = __builtin_amdgcn_readfirstlane(t >> 6);  // 0..3
    const int lr   = lane >> 3;
    const int lc   = lane & 7;
    const int bid  = blockIdx.x;
    const int rg   = bid & 255;        // rowgroup (128 rows)
    const int h    = bid >> 8;         // k-half
    const int q    = w >> 1;           // k-quarter owner (0/1)
    const int b    = rg >> 3;
    const int hw0  = (rg & 7) << 7;
    const int kb0  = h << 9;
    const int h64  = (w & 1) << 6;
    const int q64  = q << 6;
    const int rbase = h64 + lr * 8;

    const float* zg = z + (size_t)b * 65536 + hw0;

    // ---- stage zt via DMA: 32 x 1 KB linear issues (8 per wave) ----
#pragma unroll
    for (int j = 0; j < 8; ++j) {
        int d0 = ((w << 3) + j) << 1;
        gll16(zg + (size_t)(d0 + (lane >> 5)) * 1024 + ((lane & 31) << 2), &zt[d0][0]);
    }
    // ---- stage e' tile 0: 36 x 1 KB linear issues (9 per wave) ----
    {
        const float* src = g_ep + (size_t)kb0 * RL;
#pragma unroll
        for (int i = 0; i < 9; ++i) {
            int seg = w * 9 + i;                    // 0..35
            gll16(src + seg * 256 + (lane << 2), &et[seg * 256]);
        }
    }

    float best[8];
    int   bi[8];
#pragma unroll
    for (int j = 0; j < 8; ++j) { best[j] = 3.4e38f; bi[j] = 0; }

    __syncthreads();   // drain DMA

    for (int tt = 0; tt < 4; ++tt) {
        float acc[8][8];
#pragma unroll
        for (int j = 0; j < 8; ++j)
#pragma unroll
            for (int m = 0; m < 8; ++m) acc[j][m] = 0.f;

#pragma unroll 2
        for (int dq = 0; dq < 16; ++dq) {
            const int d0 = dq << 2;
            float za_[4][8];
#pragma unroll
            for (int dd = 0; dd < 4; ++dd) {
                float4 a0 = *(const float4*)&zt[d0 + dd][rbase];
                float4 a1 = *(const float4*)&zt[d0 + dd][rbase + 4];
                za_[dd][0] = a0.x; za_[dd][1] = a0.y; za_[dd][2] = a0.z; za_[dd][3] = a0.w;
                za_[dd][4] = a1.x; za_[dd][5] = a1.y; za_[dd][6] = a1.z; za_[dd][7] = a1.w;
            }
#pragma unroll
            for (int m = 0; m < 8; ++m) {
                float4 ev = *(const float4*)&et[(q64 + m * 8 + lc) * RL + d0];
                float eb_[4] = {ev.x, ev.y, ev.z, ev.w};
#pragma unroll
                for (int dd = 0; dd < 4; ++dd)
#pragma unroll
                    for (int j = 0; j < 8; ++j)
                        acc[j][m] = fmaf(za_[dd][j], eb_[dd], acc[j][m]);
            }
        }

        // merge: cand = acc + (||e||^2 + 512)  (the -2 is folded into e')
        const int ktile = kb0 + (tt << 7);
#pragma unroll
        for (int m = 0; m < 8; ++m) {
            int kk = q64 + m * 8 + lc;
            float enorm = et[kk * RL + 64];
#pragma unroll
            for (int j = 0; j < 8; ++j) {
                float cand = acc[j][m] + enorm;
                if (cand < best[j]) { best[j] = cand; bi[j] = ktile + kk; }
            }
        }
        __syncthreads();               // readers done with et

        if (tt < 3) {                  // stage next e' tile
            const float* src = g_ep + (size_t)(kb0 + ((tt + 1) << 7)) * RL;
#pragma unroll
            for (int i = 0; i < 9; ++i) {
                int seg = w * 9 + i;
                gll16(src + seg * 256 + (lane << 2), &et[seg * 256]);
            }
            __syncthreads();           // staging visible
        }
    }

    // cross-lane argmin over lc (8 lanes share (lr,j) rows); u64 min ties->min k
#pragma unroll
    for (int j = 0; j < 8; ++j) {
        unsigned long long key =
            ((unsigned long long)__float_as_uint(best[j]) << 32) | (unsigned)bi[j];
#pragma unroll
        for (int o = 1; o < 8; o <<= 1) {
            unsigned long long other = __shfl_xor(key, o, 64);
            key = other < key ? other : key;
        }
        if (lc == 0)   // one writer per (h, q, row): no race
            g_part[h][q][(size_t)rg * 128 + rbase + j] = key;
    }
}

// ---------------- kernel 2: finalize — merge 4 partials, z_q, idx, loss ----
__global__ __launch_bounds__(256) void vq_fin(const float* __restrict__ z,
                                              const float* __restrict__ e,
                                              float* __restrict__ out) {
    __shared__ float lred[4];
    int lane = threadIdx.x & 63;
    int w    = threadIdx.x >> 6;
    int rg   = blockIdx.x;          // 0..511 rowgroups of 64
    int n    = rg * 64 + lane;
    int b    = rg >> 4;
    int hw0  = (rg & 15) << 6;

    unsigned long long k00 = g_part[0][0][n];
    unsigned long long k01 = g_part[0][1][n];
    unsigned long long k10 = g_part[1][0][n];
    unsigned long long k11 = g_part[1][1][n];
    unsigned long long key = k00;
    key = k01 < key ? k01 : key;
    key = k10 < key ? k10 : key;
    key = k11 < key ? k11 : key;    // u64 min: ties -> smallest k
    int idx = (int)(key & 0xFFFFFFFFull);
    if (w == 0) out[IDX_OFF + n] = (float)idx;

    const float*  zbase = z + (size_t)b * 65536 + hw0 + lane;
    float*        qbase = out + (size_t)b * 65536 + hw0 + lane;
    const float4* er4   = (const float4*)(e + (size_t)idx * 64) + (w << 2);

    float lsum = 0.f;
#pragma unroll
    for (int p = 0; p < 4; ++p) {
        float4 ev = er4[p];                        // gather, L2-resident
        int d = (w << 4) + (p << 2);
        float ezw[4] = {ev.x, ev.y, ev.z, ev.w};
#pragma unroll
        for (int qq = 0; qq < 4; ++qq) {
            float zv = zbase[(size_t)(d + qq) * 1024];
            float df = ezw[qq] - zv;
            lsum = fmaf(df, df, lsum);
            qbase[(size_t)(d + qq) * 1024] = ezw[qq]; // coalesced along hw
        }
    }
#pragma unroll
    for (int o = 32; o; o >>= 1) lsum += __shfl_xor(lsum, o, 64);
    if (lane == 0) lred[w] = lsum;
    __syncthreads();
    if (threadIdx.x == 0)
        g_partial[rg] = (lred[0] + lred[1]) + (lred[2] + lred[3]);
}

// ---------------- kernel 3: loss scalar ------------------------------------
__global__ __launch_bounds__(64) void vq_finish(float* __restrict__ out) {
    int lane = threadIdx.x;
    float s = 0.f;
#pragma unroll
    for (int i = 0; i < 8; ++i) s += g_partial[lane * 8 + i];
#pragma unroll
    for (int o = 32; o; o >>= 1) s += __shfl_xor(s, o, 64);
    // loss = q_latent + 0.25*e_latent = 1.25 * mean((z_q - z)^2)
    if (lane == 0) out[LOSS_OFF] = s * (1.25f / 2097152.0f);
}

extern "C" void kernel_launch(void* const* d_in, const int* in_sizes, int n_in,
                              void* d_out, int out_size, void* d_ws, size_t ws_size,
                              hipStream_t stream) {
    const float* z = (const float*)d_in[0];
    const float* e = (const float*)d_in[1];
    float* out = (float*)d_out;

    vq_prep<<<256, 256, 0, stream>>>(e);
    vq_main<<<512, 256, 0, stream>>>(z);
    vq_fin<<<512, 256, 0, stream>>>(z, e, out);
    vq_finish<<<1, 64, 0, stream>>>(out);
}